// Round 1
// baseline (89.196 us; speedup 1.0000x reference)
//
#include <hip/hip_runtime.h>

#define QB 4  // queries per block, one per wave (256 threads = 4 waves)

__global__ __launch_bounds__(256, 4)
void nn_kernel(const float* __restrict__ x,
               const float* __restrict__ pts,
               const float* __restrict__ acc,
               float* __restrict__ out,
               int B, int N) {
    const int lane = threadIdx.x & 63;
    const int wave = threadIdx.x >> 6;
    const int q    = blockIdx.x * QB + wave;
    if (q >= B) return;

    const float xq = x[q];

    // Process float4 groups: G = N/4 groups, lane handles g = lane + 64*j.
    const int G = N >> 2;
    const int J = G >> 6;          // full groups per lane (N % 256 leftovers handled in tail)

    float bd0 = __builtin_inff(), bd1 = __builtin_inff(),
          bd2 = __builtin_inff(), bd3 = __builtin_inff();
    int   bj0 = 0, bj1 = 0, bj2 = 0, bj3 = 0;

    const float4* __restrict__ p4 = reinterpret_cast<const float4*>(pts);

    #pragma unroll 4
    for (int j = 0; j < J; ++j) {
        float4 v = p4[lane + 64 * j];
        float d0 = fabsf(v.x - xq);
        float d1 = fabsf(v.y - xq);
        float d2 = fabsf(v.z - xq);
        float d3 = fabsf(v.w - xq);
        // strict < keeps the FIRST (smallest j) index within each chain
        if (d0 < bd0) { bd0 = d0; bj0 = j; }
        if (d1 < bd1) { bd1 = d1; bj1 = j; }
        if (d2 < bd2) { bd2 = d2; bj2 = j; }
        if (d3 < bd3) { bd3 = d3; bj3 = j; }
    }

    // Merge the 4 per-thread chains with exact (dist, idx) lexicographic order.
    // dist >= 0 so its f32 bit pattern is monotonic as a uint.
    unsigned long long key;
    {
        unsigned i0 = (unsigned)(4 * (lane + 64 * bj0) + 0);
        unsigned i1 = (unsigned)(4 * (lane + 64 * bj1) + 1);
        unsigned i2 = (unsigned)(4 * (lane + 64 * bj2) + 2);
        unsigned i3 = (unsigned)(4 * (lane + 64 * bj3) + 3);
        unsigned long long k0 = ((unsigned long long)__float_as_uint(bd0) << 32) | i0;
        unsigned long long k1 = ((unsigned long long)__float_as_uint(bd1) << 32) | i1;
        unsigned long long k2 = ((unsigned long long)__float_as_uint(bd2) << 32) | i2;
        unsigned long long k3 = ((unsigned long long)__float_as_uint(bd3) << 32) | i3;
        key = k0 < k1 ? k0 : k1;
        unsigned long long k23 = k2 < k3 ? k2 : k3;
        key = key < k23 ? key : k23;
    }

    // Tail: elements [J*256, N) (none for N=65536, but stay generic).
    for (int i = J * 256 + lane; i < N; i += 64) {
        float d = fabsf(pts[i] - xq);
        unsigned long long k = ((unsigned long long)__float_as_uint(d) << 32) | (unsigned)i;
        key = key < k ? key : k;
    }

    // Wave-wide u64-min reduction (64 lanes, 6 butterfly steps).
    #pragma unroll
    for (int off = 1; off < 64; off <<= 1) {
        unsigned long long o = __shfl_xor(key, off, 64);
        key = key < o ? key : o;
    }

    if (lane == 0) {
        out[q] = acc[(unsigned)(key & 0xffffffffULL)];
    }
}

extern "C" void kernel_launch(void* const* d_in, const int* in_sizes, int n_in,
                              void* d_out, int out_size, void* d_ws, size_t ws_size,
                              hipStream_t stream) {
    const float* x   = (const float*)d_in[0];
    const float* pts = (const float*)d_in[1];
    const float* acc = (const float*)d_in[2];
    float* out = (float*)d_out;
    const int B = in_sizes[0];
    const int N = in_sizes[1];
    const int blocks = (B + QB - 1) / QB;
    hipLaunchKernelGGL(nn_kernel, dim3(blocks), dim3(256), 0, stream,
                       x, pts, acc, out, B, N);
}